// Round 19
// baseline (128.600 us; speedup 1.0000x reference)
//
#include <hip/hip_runtime.h>
#include <hip/hip_bf16.h>

#define NN 49
#define CC 128
#define HH 4
#define NWIN 64
#define BB 4096
#define QSCALE 0.17677669529663687f

typedef __attribute__((ext_vector_type(8))) short bf16x8;
typedef __attribute__((ext_vector_type(4))) float f32x4;
typedef unsigned short u16;
typedef unsigned int u32;

union U8 { u32 u[4]; bf16x8 v; };

__device__ __forceinline__ u16 f2b(float f) {
    __hip_bfloat16 h = __float2bfloat16(f);   // RNE (prep kernels only)
    return __builtin_bit_cast(u16, h);
}
__device__ __forceinline__ float b2f(u16 u) { return __uint_as_float(((u32)u) << 16); }
// packed f32x2 -> bf16x2 in one VALU op (RNE, same rounding as __float2bfloat16)
__device__ __forceinline__ u32 cvtpk(float lo, float hi) {
    u32 r;
    asm("v_cvt_pk_bf16_f32 %0, %1, %2" : "=v"(r) : "v"(lo), "v"(hi));
    return r;
}
__device__ __forceinline__ uint2 pack4(float a, float b, float c, float d) {
    uint2 r;
    r.x = cvtpk(a, b);
    r.y = cvtpk(c, d);
    return r;
}
__device__ __forceinline__ f32x4 mfma16(bf16x8 a, bf16x8 b, f32x4 c) {
    return __builtin_amdgcn_mfma_f32_16x16x32_bf16(a, b, c, 0, 0, 0);
}
// XOR-swizzled byte address inside a row-major LDS tile
__device__ __forceinline__ char* adr256(u16* base, int row, int byte) {
    return (char*)base + row * 256 + (byte ^ ((row & 7) << 4));
}
__device__ __forceinline__ char* adr128(u16* base, int row, int byte) {
    return (char*)base + row * 128 + (byte ^ ((row & 7) << 4));
}

// ---- prep 1: cb_t[w][h][i][m] = bias[rel[i,m]][h] + mask[w][i][m]  (bf16, -1e9 pads) ----
__global__ void prep_cbt(const float* __restrict__ bias_table, const int* __restrict__ rel_idx,
                         const float* __restrict__ mask, u16* __restrict__ cbt) {
    int idx = blockIdx.x * blockDim.x + threadIdx.x;
    int m = idx & 63, i = (idx >> 6) & 63, h = (idx >> 12) & 3, wv = idx >> 14;
    if (wv >= NWIN) return;
    float v = -1e9f;
    if (m < NN && i < NN)
        v = bias_table[rel_idx[i * NN + m] * HH + h] + mask[(wv * NN + i) * NN + m];
    cbt[idx] = f2b(v);
}

// ---- prep 2: pack weights into exact fragment layout, bf16 ----
// packed[nt][kt][lane][i] = W[32kt + 8*(lane>>4) + i][16nt + (lane&15)]
__global__ void prep_w(const float* __restrict__ qw, const float* __restrict__ qb,
                       const float* __restrict__ kvw, const float* __restrict__ pjw,
                       u16* __restrict__ qwp, u16* __restrict__ kvwp,
                       u16* __restrict__ pjwp, float* __restrict__ qbs) {
    int idx = blockIdx.x * blockDim.x + threadIdx.x;
    if (idx < 16384) {
        int i = idx & 7, lane = (idx >> 3) & 63, kt = (idx >> 9) & 3, nt = idx >> 11;
        int k = 32 * kt + 8 * (lane >> 4) + i, n = 16 * nt + (lane & 15);
        qwp[idx] = f2b(qw[k * CC + n] * QSCALE);
    } else if (idx < 49152) {
        int j = idx - 16384;
        int i = j & 7, lane = (j >> 3) & 63, kt = (j >> 9) & 3, nt = j >> 11;
        int k = 32 * kt + 8 * (lane >> 4) + i, n = 16 * nt + (lane & 15);
        kvwp[j] = f2b(kvw[k * 2 * CC + n]);
    } else if (idx < 65536) {
        int j = idx - 49152;
        int i = j & 7, lane = (j >> 3) & 63, kt = (j >> 9) & 3, nt = j >> 11;
        int k = 32 * kt + 8 * (lane >> 4) + i, n = 16 * nt + (lane & 15);
        pjwp[j] = f2b(pjw[k * CC + n]);
    } else if (idx < 65664) {
        int j = idx - 65536;
        qbs[j] = qb[j] * QSCALE;
    }
}

// ---- main fused kernel: one block/window, 4 waves, 48KB LDS -> 3 blocks/CU ----
// r12-quality phases on the 256-thread shape: 3 independent barrier domains/CU
// (r4-vs-r6 evidence: 3 domains x 4 waves beat 2 domains x 8 waves). Wave w:
// GEMM nt={w,w+4} over all 4 mt; attention head h=w over all 4 bq (r2 tiling).
// R0: Xq -> k -> P scratch; R1: q -> x; R2: Xs -> v^T. 5 barriers.
// (256,3) caps VGPR at 170 (est. live set ~150; r2 measured 120 with fatter code).
__global__ __launch_bounds__(256, 3)
void wmha_main(const float* __restrict__ query, const float* __restrict__ source,
               const u16* __restrict__ qwp, const u16* __restrict__ kvwp,
               const u16* __restrict__ pjwp, const float* __restrict__ qbs,
               const float* __restrict__ kv_b, const float* __restrict__ proj_b,
               const u16* __restrict__ cbt, float* __restrict__ out) {
    __shared__ u16 lds[24576];        // 48 KB
    u16* R0 = lds;                    // Xq -> k -> P scratch (4 waves x 4KB)
    u16* R1 = lds + 8192;             // q -> x
    u16* R2 = lds + 16384;            // Xs -> v^T
    const int t = threadIdx.x;
    const int b = blockIdx.x;
    const int w = t >> 6, lane = t & 63;
    const int lq = lane & 15, qd = lane >> 4;
    const int h = w;                  // attention head = wave

    // ---- stage Xq->R0 and Xs->R2 (bf16 via cvt_pk, zero-pad rows 49..63) ----
    {
        const int row = t >> 2, qu = t & 3;
        const size_t gbase = (size_t)b * NN * CC + row * CC + qu * 32;
        #pragma unroll
        for (int j = 0; j < 4; ++j) {
            U8 vq, vs;
            if (row < NN) {
                const float4* q4 = (const float4*)(query + gbase) + 2 * j;
                const float4* s4 = (const float4*)(source + gbase) + 2 * j;
                float4 a0 = q4[0], a1 = q4[1], c0 = s4[0], c1 = s4[1];
                vq.u[0] = cvtpk(a0.x, a0.y); vq.u[1] = cvtpk(a0.z, a0.w);
                vq.u[2] = cvtpk(a1.x, a1.y); vq.u[3] = cvtpk(a1.z, a1.w);
                vs.u[0] = cvtpk(c0.x, c0.y); vs.u[1] = cvtpk(c0.z, c0.w);
                vs.u[2] = cvtpk(c1.x, c1.y); vs.u[3] = cvtpk(c1.z, c1.w);
            } else {
                vq.u[0] = vq.u[1] = vq.u[2] = vq.u[3] = 0;
                vs.u[0] = vs.u[1] = vs.u[2] = vs.u[3] = 0;
            }
            *(bf16x8*)adr256(R0, row, qu * 64 + 16 * j) = vq.v;
            *(bf16x8*)adr256(R2, row, qu * 64 + 16 * j) = vs.v;
        }
    }
    // GEMM1 B-frags prefetched pre-barrier (only these — r9 lesson)
    bf16x8 bwq[2][4];
    #pragma unroll
    for (int n2 = 0; n2 < 2; ++n2)
        #pragma unroll
        for (int kt = 0; kt < 4; ++kt)
            bwq[n2][kt] = *(const bf16x8*)(qwp + (((w + 4 * n2) * 4 + kt) * 64 + lane) * 8);
    __syncthreads();  // bar0: inputs staged

    // ---- GEMM1 (swapped): q = Xq @ qw_scaled -> R1 [tok][chan]; nt={w,w+4}, mt=0..3 ----
    {
        f32x4 acc[4][2] = {};
        #pragma unroll
        for (int mt = 0; mt < 4; ++mt) {
            bf16x8 a[4];
            #pragma unroll
            for (int kt = 0; kt < 4; ++kt)
                a[kt] = *(const bf16x8*)adr256(R0, mt * 16 + lq, kt * 64 + qd * 16);
            __builtin_amdgcn_s_setprio(1);
            #pragma unroll
            for (int n2 = 0; n2 < 2; ++n2)
                #pragma unroll
                for (int kt = 0; kt < 4; ++kt)
                    acc[mt][n2] = mfma16(bwq[n2][kt], a[kt], acc[mt][n2]);
            __builtin_amdgcn_s_setprio(0);
        }
        #pragma unroll
        for (int n2 = 0; n2 < 2; ++n2) {
            const int cb0 = 16 * (w + 4 * n2) + 4 * qd;
            const float4 bia = *(const float4*)(qbs + cb0);
            #pragma unroll
            for (int mt = 0; mt < 4; ++mt) {
                const int tok = mt * 16 + lq;
                uint2 pk = pack4(acc[mt][n2][0] + bia.x, acc[mt][n2][1] + bia.y,
                                 acc[mt][n2][2] + bia.z, acc[mt][n2][3] + bia.w);
                *(uint2*)adr256(R1, tok, 2 * cb0) = pk;
            }
        }
    }
    __syncthreads();  // bar1: all GEMM1 reads of R0 done -> R0 writable (k)

    // ---- GEMM2k (swapped): k = Xs @ kvw[:, :128] -> R0 ----
    {
        bf16x8 bwk[2][4];
        #pragma unroll
        for (int n2 = 0; n2 < 2; ++n2)
            #pragma unroll
            for (int kt = 0; kt < 4; ++kt)
                bwk[n2][kt] = *(const bf16x8*)(kvwp + (((w + 4 * n2) * 4 + kt) * 64 + lane) * 8);
        f32x4 acc[4][2] = {};
        #pragma unroll
        for (int mt = 0; mt < 4; ++mt) {
            bf16x8 a[4];
            #pragma unroll
            for (int kt = 0; kt < 4; ++kt)
                a[kt] = *(const bf16x8*)adr256(R2, mt * 16 + lq, kt * 64 + qd * 16);
            __builtin_amdgcn_s_setprio(1);
            #pragma unroll
            for (int n2 = 0; n2 < 2; ++n2)
                #pragma unroll
                for (int kt = 0; kt < 4; ++kt)
                    acc[mt][n2] = mfma16(bwk[n2][kt], a[kt], acc[mt][n2]);
            __builtin_amdgcn_s_setprio(0);
        }
        #pragma unroll
        for (int n2 = 0; n2 < 2; ++n2) {
            const int cb0 = 16 * (w + 4 * n2) + 4 * qd;
            const float4 bia = *(const float4*)(kv_b + cb0);
            #pragma unroll
            for (int mt = 0; mt < 4; ++mt) {
                const int tok = mt * 16 + lq;
                uint2 pk = pack4(acc[mt][n2][0] + bia.x, acc[mt][n2][1] + bia.y,
                                 acc[mt][n2][2] + bia.z, acc[mt][n2][3] + bia.w);
                *(uint2*)adr256(R0, tok, 2 * cb0) = pk;
            }
        }
    }

    // ---- GEMM2v (plain): v = Xs @ kvw[:, 128:]; pre-packed, v^T written post-bar2 ----
    {
        bf16x8 bwv[2][4];
        #pragma unroll
        for (int n2 = 0; n2 < 2; ++n2)
            #pragma unroll
            for (int kt = 0; kt < 4; ++kt)
                bwv[n2][kt] = *(const bf16x8*)(kvwp + (((8 + w + 4 * n2) * 4 + kt) * 64 + lane) * 8);
        f32x4 acc[4][2] = {};
        #pragma unroll
        for (int mt = 0; mt < 4; ++mt) {
            bf16x8 a[4];
            #pragma unroll
            for (int kt = 0; kt < 4; ++kt)
                a[kt] = *(const bf16x8*)adr256(R2, mt * 16 + lq, kt * 64 + qd * 16);
            __builtin_amdgcn_s_setprio(1);
            #pragma unroll
            for (int n2 = 0; n2 < 2; ++n2)
                #pragma unroll
                for (int kt = 0; kt < 4; ++kt)
                    acc[mt][n2] = mfma16(a[kt], bwv[n2][kt], acc[mt][n2]);
            __builtin_amdgcn_s_setprio(0);
        }
        uint2 pkv[2][4];
        #pragma unroll
        for (int n2 = 0; n2 < 2; ++n2) {
            const float bias = kv_b[CC + 16 * (w + 4 * n2) + lq];
            #pragma unroll
            for (int mt = 0; mt < 4; ++mt)
                pkv[n2][mt] = pack4(acc[mt][n2][0] + bias, acc[mt][n2][1] + bias,
                                    acc[mt][n2][2] + bias, acc[mt][n2][3] + bias);
        }
        __syncthreads();  // bar2: k visible; all Xs (R2) reads done
        #pragma unroll
        for (int n2 = 0; n2 < 2; ++n2) {
            const int dim = 16 * (w + 4 * n2) + lq;
            #pragma unroll
            for (int mt = 0; mt < 4; ++mt)
                *(uint2*)adr128(R2, dim, 2 * (mt * 16 + qd * 4)) = pkv[n2][mt];
        }
    }

    // ---- QK^T (swapped): S^T[key][query]; wave = head h, all 4 bq ----
    f32x4 s[4][4];
    {
        bf16x8 kf[4], qf[4];
        #pragma unroll
        for (int a = 0; a < 4; ++a)
            kf[a] = *(const bf16x8*)adr256(R0, a * 16 + lq, h * 64 + qd * 16);
        #pragma unroll
        for (int bq = 0; bq < 4; ++bq)
            qf[bq] = *(const bf16x8*)adr256(R1, bq * 16 + lq, h * 64 + qd * 16);
        __builtin_amdgcn_s_setprio(1);
        #pragma unroll
        for (int bq = 0; bq < 4; ++bq) {
            f32x4 z = {0.f, 0.f, 0.f, 0.f};
            #pragma unroll
            for (int a = 0; a < 4; ++a)
                s[bq][a] = mfma16(kf[a], qf[bq], z);
        }
        __builtin_amdgcn_s_setprio(0);
    }
    // bias tiles: issued pre-barrier, latency hides under the wait
    uint2 cbr[4][4];
    {
        const u16* cbb = cbt + ((size_t)((b & (NWIN - 1)) * HH + h) << 12);
        #pragma unroll
        for (int bq = 0; bq < 4; ++bq)
            #pragma unroll
            for (int a = 0; a < 4; ++a)
                cbr[bq][a] = *(const uint2*)(cbb + (bq * 16 + lq) * 64 + a * 16 + qd * 4);
    }
    __syncthreads();  // bar3: v^T visible; q/k reads done -> R0 = P scratch, R1 = x

    // ---- softmax + PV: 2 pairs of bq, double P buffer, ONE fence per pair ----
    {
        bf16x8 vf[2][2];
        #pragma unroll
        for (int dt = 0; dt < 2; ++dt)
            #pragma unroll
            for (int kt = 0; kt < 2; ++kt)
                vf[dt][kt] = *(const bf16x8*)adr128(R2, h * 32 + dt * 16 + lq, kt * 64 + qd * 16);
        u16* pb0 = R0 + w * 2048;   // 4 waves x 4KB = 16KB = all of R0
        u16* pb1 = pb0 + 1024;
        #pragma unroll
        for (int p = 0; p < 2; ++p) {
            float inv[2];
            #pragma unroll
            for (int i = 0; i < 2; ++i) {
                const int bq = 2 * p + i;
                #pragma unroll
                for (int a = 0; a < 4; ++a) {
                    s[bq][a][0] += b2f((u16)(cbr[bq][a].x & 0xffffu));
                    s[bq][a][1] += b2f((u16)(cbr[bq][a].x >> 16));
                    s[bq][a][2] += b2f((u16)(cbr[bq][a].y & 0xffffu));
                    s[bq][a][3] += b2f((u16)(cbr[bq][a].y >> 16));
                }
                float m0 = s[bq][0][0];
                #pragma unroll
                for (int a = 0; a < 4; ++a)
                    #pragma unroll
                    for (int r = 0; r < 4; ++r) m0 = fmaxf(m0, s[bq][a][r]);
                m0 = fmaxf(m0, __shfl_xor(m0, 16));
                m0 = fmaxf(m0, __shfl_xor(m0, 32));
                uint2 pk[4];
                float sm = 0.f;
                #pragma unroll
                for (int a = 0; a < 4; ++a) {
                    float p0 = __expf(s[bq][a][0] - m0), p1 = __expf(s[bq][a][1] - m0);
                    float p2 = __expf(s[bq][a][2] - m0), p3 = __expf(s[bq][a][3] - m0);
                    pk[a].x = cvtpk(p0, p1);
                    pk[a].y = cvtpk(p2, p3);
                    sm += (p0 + p1) + (p2 + p3);   // f32 sum (pre-rounding)
                }
                sm += __shfl_xor(sm, 16);
                sm += __shfl_xor(sm, 32);
                inv[i] = 1.f / sm;
                u16* pb = i ? pb1 : pb0;
                #pragma unroll
                for (int a = 0; a < 4; ++a)
                    *(uint2*)adr128(pb, lq, 32 * a + 8 * qd) = pk[a];
            }
            // single drain per pair; pin schedule (r4-proven pattern)
            asm volatile("s_waitcnt lgkmcnt(0)" ::: "memory");
            __builtin_amdgcn_sched_barrier(0);
            f32x4 o[2][2] = {};
            __builtin_amdgcn_s_setprio(1);
            #pragma unroll
            for (int kt = 0; kt < 2; ++kt) {
                bf16x8 pf0 = *(const bf16x8*)adr128(pb0, lq, 64 * kt + 16 * qd);
                bf16x8 pf1 = *(const bf16x8*)adr128(pb1, lq, 64 * kt + 16 * qd);
                #pragma unroll
                for (int dt = 0; dt < 2; ++dt) {
                    o[0][dt] = mfma16(vf[dt][kt], pf0, o[0][dt]);
                    o[1][dt] = mfma16(vf[dt][kt], pf1, o[1][dt]);
                }
            }
            __builtin_amdgcn_s_setprio(0);
            __builtin_amdgcn_sched_barrier(0);  // keep next pair's P stores below these reads
            #pragma unroll
            for (int i = 0; i < 2; ++i)
                #pragma unroll
                for (int dt = 0; dt < 2; ++dt) {
                    uint2 px = pack4(o[i][dt][0] * inv[i], o[i][dt][1] * inv[i],
                                     o[i][dt][2] * inv[i], o[i][dt][3] * inv[i]);
                    *(uint2*)adr256(R1, (2 * p + i) * 16 + lq, 64 * h + 32 * dt + 8 * qd) = px;
                }
        }
    }

    // ---- GEMM3 (swapped): out = x @ pjw + proj_b; coalesced float4 stores ----
    {
        bf16x8 bw[2][4];
        #pragma unroll
        for (int n2 = 0; n2 < 2; ++n2)
            #pragma unroll
            for (int kt = 0; kt < 4; ++kt)
                bw[n2][kt] = *(const bf16x8*)(pjwp + (((w + 4 * n2) * 4 + kt) * 64 + lane) * 8);
        __syncthreads();  // bar4: x complete in R1
        f32x4 acc[4][2] = {};
        #pragma unroll
        for (int mt = 0; mt < 4; ++mt) {
            bf16x8 a[4];
            #pragma unroll
            for (int kt = 0; kt < 4; ++kt)
                a[kt] = *(const bf16x8*)adr256(R1, mt * 16 + lq, kt * 64 + qd * 16);
            __builtin_amdgcn_s_setprio(1);
            #pragma unroll
            for (int n2 = 0; n2 < 2; ++n2)
                #pragma unroll
                for (int kt = 0; kt < 4; ++kt)
                    acc[mt][n2] = mfma16(bw[n2][kt], a[kt], acc[mt][n2]);
            __builtin_amdgcn_s_setprio(0);
        }
        float* outb = out + (size_t)b * NN * CC;
        #pragma unroll
        for (int n2 = 0; n2 < 2; ++n2) {
            const int cb0 = 16 * (w + 4 * n2) + 4 * qd;
            const float4 bia = *(const float4*)(proj_b + cb0);
            #pragma unroll
            for (int mt = 0; mt < 4; ++mt) {
                const int tok = mt * 16 + lq;
                if (tok < NN) {
                    float4 vst;
                    vst.x = acc[mt][n2][0] + bia.x;
                    vst.y = acc[mt][n2][1] + bia.y;
                    vst.z = acc[mt][n2][2] + bia.z;
                    vst.w = acc[mt][n2][3] + bia.w;
                    *(float4*)(outb + tok * CC + cb0) = vst;
                }
            }
        }
    }
}

extern "C" void kernel_launch(void* const* d_in, const int* in_sizes, int n_in,
                              void* d_out, int out_size, void* d_ws, size_t ws_size,
                              hipStream_t stream) {
    const float* query      = (const float*)d_in[0];
    const float* source     = (const float*)d_in[1];
    const float* mask       = (const float*)d_in[2];
    const float* q_w        = (const float*)d_in[3];
    const float* q_b        = (const float*)d_in[4];
    const float* kv_w       = (const float*)d_in[5];
    const float* kv_b       = (const float*)d_in[6];
    const float* proj_w     = (const float*)d_in[7];
    const float* proj_b     = (const float*)d_in[8];
    const float* bias_table = (const float*)d_in[9];
    const int*   rel_idx    = (const int*)d_in[10];
    float* out = (float*)d_out;

    u16* cbt   = (u16*)d_ws;              // 1 Mi u16 = 2 MB
    u16* qwp   = cbt + 1048576;           // 16384 u16
    u16* kvwp  = qwp + 16384;             // 32768 u16
    u16* pjwp  = kvwp + 32768;            // 16384 u16
    float* qbs = (float*)(pjwp + 16384);  // 128 f32

    prep_cbt<<<4096, 256, 0, stream>>>(bias_table, rel_idx, mask, cbt);
    prep_w<<<257, 256, 0, stream>>>(q_w, q_b, kv_w, proj_w, qwp, kvwp, pjwp, qbs);
    wmha_main<<<BB, 256, 0, stream>>>(query, source, qwp, kvwp, pjwp, qbs,
                                      kv_b, proj_b, cbt, out);
}

// Round 20
// 121.634 us; speedup vs baseline: 1.0573x; 1.0573x over previous
//
#include <hip/hip_runtime.h>
#include <hip/hip_bf16.h>

#define NN 49
#define CC 128
#define HH 4
#define NWIN 64
#define BB 4096
#define QSCALE 0.17677669529663687f

typedef __attribute__((ext_vector_type(8))) short bf16x8;
typedef __attribute__((ext_vector_type(4))) float f32x4;
typedef unsigned short u16;
typedef unsigned int u32;

union U8 { u32 u[4]; bf16x8 v; };

__device__ __forceinline__ u16 f2b(float f) {
    __hip_bfloat16 h = __float2bfloat16(f);   // RNE (prep kernels only)
    return __builtin_bit_cast(u16, h);
}
__device__ __forceinline__ float b2f(u16 u) { return __uint_as_float(((u32)u) << 16); }
// packed f32x2 -> bf16x2 in one VALU op (RNE, same rounding as __float2bfloat16)
__device__ __forceinline__ u32 cvtpk(float lo, float hi) {
    u32 r;
    asm("v_cvt_pk_bf16_f32 %0, %1, %2" : "=v"(r) : "v"(lo), "v"(hi));
    return r;
}
__device__ __forceinline__ uint2 pack4(float a, float b, float c, float d) {
    uint2 r;
    r.x = cvtpk(a, b);
    r.y = cvtpk(c, d);
    return r;
}
__device__ __forceinline__ f32x4 mfma16(bf16x8 a, bf16x8 b, f32x4 c) {
    return __builtin_amdgcn_mfma_f32_16x16x32_bf16(a, b, c, 0, 0, 0);
}
// XOR-swizzled byte address inside a row-major LDS tile
__device__ __forceinline__ char* adr256(u16* base, int row, int byte) {
    return (char*)base + row * 256 + (byte ^ ((row & 7) << 4));
}
__device__ __forceinline__ char* adr128(u16* base, int row, int byte) {
    return (char*)base + row * 128 + (byte ^ ((row & 7) << 4));
}

// ---- prep 1: cb_t[w][h][i][m] = bias[rel[i,m]][h] + mask[w][i][m]  (bf16, -1e9 pads) ----
__global__ void prep_cbt(const float* __restrict__ bias_table, const int* __restrict__ rel_idx,
                         const float* __restrict__ mask, u16* __restrict__ cbt) {
    int idx = blockIdx.x * blockDim.x + threadIdx.x;
    int m = idx & 63, i = (idx >> 6) & 63, h = (idx >> 12) & 3, wv = idx >> 14;
    if (wv >= NWIN) return;
    float v = -1e9f;
    if (m < NN && i < NN)
        v = bias_table[rel_idx[i * NN + m] * HH + h] + mask[(wv * NN + i) * NN + m];
    cbt[idx] = f2b(v);
}

// ---- prep 2: pack weights into exact fragment layout, bf16 ----
// packed[nt][kt][lane][i] = W[32kt + 8*(lane>>4) + i][16nt + (lane&15)]
__global__ void prep_w(const float* __restrict__ qw, const float* __restrict__ qb,
                       const float* __restrict__ kvw, const float* __restrict__ pjw,
                       u16* __restrict__ qwp, u16* __restrict__ kvwp,
                       u16* __restrict__ pjwp, float* __restrict__ qbs) {
    int idx = blockIdx.x * blockDim.x + threadIdx.x;
    if (idx < 16384) {
        int i = idx & 7, lane = (idx >> 3) & 63, kt = (idx >> 9) & 3, nt = idx >> 11;
        int k = 32 * kt + 8 * (lane >> 4) + i, n = 16 * nt + (lane & 15);
        qwp[idx] = f2b(qw[k * CC + n] * QSCALE);
    } else if (idx < 49152) {
        int j = idx - 16384;
        int i = j & 7, lane = (j >> 3) & 63, kt = (j >> 9) & 3, nt = j >> 11;
        int k = 32 * kt + 8 * (lane >> 4) + i, n = 16 * nt + (lane & 15);
        kvwp[j] = f2b(kvw[k * 2 * CC + n]);
    } else if (idx < 65536) {
        int j = idx - 49152;
        int i = j & 7, lane = (j >> 3) & 63, kt = (j >> 9) & 3, nt = j >> 11;
        int k = 32 * kt + 8 * (lane >> 4) + i, n = 16 * nt + (lane & 15);
        pjwp[j] = f2b(pjw[k * CC + n]);
    } else if (idx < 65664) {
        int j = idx - 65536;
        qbs[j] = qb[j] * QSCALE;
    }
}

// ---- main fused kernel: one block/window, 8 waves, 80KB LDS, 4 barriers ----
// SESSION OPTIMUM (121.7us, measured r12 & r18). Structure: 5 dedicated LDS
// regions, swapped-operand GEMMs (uint2 LDS / float4 global epilogues),
// swapped QK^T, double-P-buffer PV with a single lgkmcnt fence, cvt_pk
// conversions, f32-sum softmax with pad-tile shortcut.
// Measured constraints on this part (do not revisit):
// - 512-thread blocks cap at 2/CU regardless of VGPR/LDS headroom (r17);
//   256-thread/3-domain is worse (r19: 128.6, conflicts +26%).
// - min-waves >=6 at 512 threads forces spills (r5, r13: VGPR->40, +260MB scratch).
// - latency-bound attractor, not pipe roofline: all pipes <=25%; barrier count,
//   fence count, VALU diet, softmax-max removal, mega-prefetch, persistent
//   blocks, kernel split, in-register P exchange all neutral-to-worse (r8-r19).
__global__ __launch_bounds__(512, 2)
void wmha_main(const float* __restrict__ query, const float* __restrict__ source,
               const u16* __restrict__ qwp, const u16* __restrict__ kvwp,
               const u16* __restrict__ pjwp, const float* __restrict__ qbs,
               const float* __restrict__ kv_b, const float* __restrict__ proj_b,
               const u16* __restrict__ cbt, float* __restrict__ out) {
    __shared__ u16 lds[40960];        // 80 KB
    u16* SQ = lds;                    // staged Xq [64][128]; phase2+: x buffer
    u16* SS = lds + 8192;             // staged Xs [64][128]
    u16* Qb = lds + 16384;            // q [64][128]; post-QK: P buf i=0
    u16* Kb = lds + 24576;            // k [64][128]; post-QK: P buf i=1
    u16* VT = lds + 32768;            // v^T [128 dim][64 tok]
    const int t = threadIdx.x;
    const int b = blockIdx.x;
    const int w = t >> 6, lane = t & 63;
    const int lq = lane & 15, qd = lane >> 4;
    const int mw = w >> 2;            // token-tile half (0..1)
    const int nw = w & 3;             // chan-tile group (0..3)
    const int h = w >> 1;             // attention head (0..3)
    const int half = w & 1;           // attention bq-half

    // ---- stage Xq->SQ and Xs->SS (bf16 via cvt_pk, zero-pad rows 49..63) ----
    {
        const int row = t >> 3, qu = t & 7;
        const size_t gbase = (size_t)b * NN * CC + row * CC + qu * 8;
        #pragma unroll
        for (int j = 0; j < 2; ++j) {
            U8 vq, vs;
            if (row < NN) {
                const float4* q4 = (const float4*)(query + gbase) + 16 * j;
                const float4* s4 = (const float4*)(source + gbase) + 16 * j;
                float4 a0 = q4[0], a1 = q4[1], c0 = s4[0], c1 = s4[1];
                vq.u[0] = cvtpk(a0.x, a0.y); vq.u[1] = cvtpk(a0.z, a0.w);
                vq.u[2] = cvtpk(a1.x, a1.y); vq.u[3] = cvtpk(a1.z, a1.w);
                vs.u[0] = cvtpk(c0.x, c0.y); vs.u[1] = cvtpk(c0.z, c0.w);
                vs.u[2] = cvtpk(c1.x, c1.y); vs.u[3] = cvtpk(c1.z, c1.w);
            } else {
                vq.u[0] = vq.u[1] = vq.u[2] = vq.u[3] = 0;
                vs.u[0] = vs.u[1] = vs.u[2] = vs.u[3] = 0;
            }
            *(bf16x8*)adr256(SQ, row, qu * 16 + 128 * j) = vq.v;
            *(bf16x8*)adr256(SS, row, qu * 16 + 128 * j) = vs.v;
        }
    }
    // GEMM1 B-frags prefetched pre-barrier (only these — r9 lesson)
    bf16x8 bwq[2][4];
    #pragma unroll
    for (int n2 = 0; n2 < 2; ++n2)
        #pragma unroll
        for (int kt = 0; kt < 4; ++kt)
            bwq[n2][kt] = *(const bf16x8*)(qwp + (((nw + 4 * n2) * 4 + kt) * 64 + lane) * 8);
    __syncthreads();  // bar0: inputs staged

    // ============ PHASE 1: all three projections, no internal barriers ============
    // ---- GEMM1 (swapped): q = Xq @ qw_scaled -> Qb [tok][chan] ----
    {
        f32x4 acc[2][2] = {};
        #pragma unroll
        for (int m2 = 0; m2 < 2; ++m2) {
            bf16x8 a[4];
            #pragma unroll
            for (int kt = 0; kt < 4; ++kt)
                a[kt] = *(const bf16x8*)adr256(SQ, (2 * mw + m2) * 16 + lq, kt * 64 + qd * 16);
            __builtin_amdgcn_s_setprio(1);
            #pragma unroll
            for (int n2 = 0; n2 < 2; ++n2)
                #pragma unroll
                for (int kt = 0; kt < 4; ++kt)
                    acc[m2][n2] = mfma16(bwq[n2][kt], a[kt], acc[m2][n2]);
            __builtin_amdgcn_s_setprio(0);
        }
        #pragma unroll
        for (int n2 = 0; n2 < 2; ++n2) {
            const int cb0 = 16 * (nw + 4 * n2) + 4 * qd;
            const float4 bia = *(const float4*)(qbs + cb0);
            #pragma unroll
            for (int m2 = 0; m2 < 2; ++m2) {
                const int tok = (2 * mw + m2) * 16 + lq;
                uint2 pk = pack4(acc[m2][n2][0] + bia.x, acc[m2][n2][1] + bia.y,
                                 acc[m2][n2][2] + bia.z, acc[m2][n2][3] + bia.w);
                *(uint2*)adr256(Qb, tok, 2 * cb0) = pk;
            }
        }
    }
    // ---- GEMM2: shared A-frags from SS; k (swapped) -> Kb, v (plain) -> VT ----
    {
        bf16x8 as[2][4];
        #pragma unroll
        for (int m2 = 0; m2 < 2; ++m2)
            #pragma unroll
            for (int kt = 0; kt < 4; ++kt)
                as[m2][kt] = *(const bf16x8*)adr256(SS, (2 * mw + m2) * 16 + lq, kt * 64 + qd * 16);
        {   // k
            bf16x8 bwk[2][4];
            #pragma unroll
            for (int n2 = 0; n2 < 2; ++n2)
                #pragma unroll
                for (int kt = 0; kt < 4; ++kt)
                    bwk[n2][kt] = *(const bf16x8*)(kvwp + (((nw + 4 * n2) * 4 + kt) * 64 + lane) * 8);
            f32x4 acc[2][2] = {};
            __builtin_amdgcn_s_setprio(1);
            #pragma unroll
            for (int m2 = 0; m2 < 2; ++m2)
                #pragma unroll
                for (int n2 = 0; n2 < 2; ++n2)
                    #pragma unroll
                    for (int kt = 0; kt < 4; ++kt)
                        acc[m2][n2] = mfma16(bwk[n2][kt], as[m2][kt], acc[m2][n2]);
            __builtin_amdgcn_s_setprio(0);
            #pragma unroll
            for (int n2 = 0; n2 < 2; ++n2) {
                const int cb0 = 16 * (nw + 4 * n2) + 4 * qd;
                const float4 bia = *(const float4*)(kv_b + cb0);
                #pragma unroll
                for (int m2 = 0; m2 < 2; ++m2) {
                    const int tok = (2 * mw + m2) * 16 + lq;
                    uint2 pk = pack4(acc[m2][n2][0] + bia.x, acc[m2][n2][1] + bia.y,
                                     acc[m2][n2][2] + bia.z, acc[m2][n2][3] + bia.w);
                    *(uint2*)adr256(Kb, tok, 2 * cb0) = pk;
                }
            }
        }
        {   // v -> v^T
            bf16x8 bwv[2][4];
            #pragma unroll
            for (int n2 = 0; n2 < 2; ++n2)
                #pragma unroll
                for (int kt = 0; kt < 4; ++kt)
                    bwv[n2][kt] = *(const bf16x8*)(kvwp + (((8 + nw + 4 * n2) * 4 + kt) * 64 + lane) * 8);
            f32x4 acc[2][2] = {};
            __builtin_amdgcn_s_setprio(1);
            #pragma unroll
            for (int m2 = 0; m2 < 2; ++m2)
                #pragma unroll
                for (int n2 = 0; n2 < 2; ++n2)
                    #pragma unroll
                    for (int kt = 0; kt < 4; ++kt)
                        acc[m2][n2] = mfma16(as[m2][kt], bwv[n2][kt], acc[m2][n2]);
            __builtin_amdgcn_s_setprio(0);
            #pragma unroll
            for (int n2 = 0; n2 < 2; ++n2) {
                const int dim = 16 * (nw + 4 * n2) + lq;
                const float bias = kv_b[CC + dim];
                #pragma unroll
                for (int m2 = 0; m2 < 2; ++m2) {
                    uint2 pk = pack4(acc[m2][n2][0] + bias, acc[m2][n2][1] + bias,
                                     acc[m2][n2][2] + bias, acc[m2][n2][3] + bias);
                    *(uint2*)adr128(VT, dim, 2 * ((2 * mw + m2) * 16 + qd * 4)) = pk;
                }
            }
        }
    }
    __syncthreads();  // bar1: q, k, v^T complete; SQ/SS dead

    // ============ PHASE 2a: QK^T (swapped): S^T[key][query] ============
    f32x4 s[2][4];
    bf16x8 vf[2][2];
    {
        bf16x8 kf[4], qf[2];
        #pragma unroll
        for (int a = 0; a < 4; ++a)
            kf[a] = *(const bf16x8*)adr256(Kb, a * 16 + lq, h * 64 + qd * 16);
        #pragma unroll
        for (int i = 0; i < 2; ++i)
            qf[i] = *(const bf16x8*)adr256(Qb, (2 * half + i) * 16 + lq, h * 64 + qd * 16);
        __builtin_amdgcn_s_setprio(1);
        #pragma unroll
        for (int i = 0; i < 2; ++i) {
            f32x4 z = {0.f, 0.f, 0.f, 0.f};
            #pragma unroll
            for (int a = 0; a < 4; ++a)
                s[i][a] = mfma16(kf[a], qf[i], z);
        }
        __builtin_amdgcn_s_setprio(0);
        #pragma unroll
        for (int dt = 0; dt < 2; ++dt)
            #pragma unroll
            for (int kt = 0; kt < 2; ++kt)
                vf[dt][kt] = *(const bf16x8*)adr128(VT, h * 32 + dt * 16 + lq, kt * 64 + qd * 16);
    }
    // bias tiles: global loads issued pre-barrier (latency hides under the wait)
    uint2 cbr[2][4];
    {
        const u16* cbb = cbt + ((size_t)((b & (NWIN - 1)) * HH + h) << 12);
        #pragma unroll
        for (int i = 0; i < 2; ++i)
            #pragma unroll
            for (int a = 0; a < 4; ++a)
                cbr[i][a] = *(const uint2*)(cbb + ((2 * half + i) * 16 + lq) * 64 + a * 16 + qd * 4);
    }
    __syncthreads();  // bar1.5: all Qb/Kb reads done -> both become P scratch

    // ============ PHASE 2b: softmax x2 -> P0/P1, ONE fence, PV x2 ============
    {
        u16* pb0 = Qb + w * 1024;  // per-wave [16 q][64 k] bf16
        u16* pb1 = Kb + w * 1024;
        float inv[2];
        #pragma unroll
        for (int i = 0; i < 2; ++i) {
            // bias add: tiles a=0..2 full; tile a=3 only elem 0 (key 48 is the
            // only real key; other slots never used — pads hardwired to 0 below)
            #pragma unroll
            for (int a = 0; a < 3; ++a) {
                s[i][a][0] += b2f((u16)(cbr[i][a].x & 0xffffu));
                s[i][a][1] += b2f((u16)(cbr[i][a].x >> 16));
                s[i][a][2] += b2f((u16)(cbr[i][a].y & 0xffffu));
                s[i][a][3] += b2f((u16)(cbr[i][a].y >> 16));
            }
            s[i][3][0] += b2f((u16)(cbr[i][3].x & 0xffffu));
            float m0 = s[i][3][0];   // -1e9 for qd!=0 lanes: harmless in max
            #pragma unroll
            for (int a = 0; a < 3; ++a)
                #pragma unroll
                for (int r = 0; r < 4; ++r) m0 = fmaxf(m0, s[i][a][r]);
            m0 = fmaxf(m0, __shfl_xor(m0, 16));
            m0 = fmaxf(m0, __shfl_xor(m0, 32));
            uint2 pk[4];
            float sm = 0.f;
            #pragma unroll
            for (int a = 0; a < 3; ++a) {
                float p0 = __expf(s[i][a][0] - m0), p1 = __expf(s[i][a][1] - m0);
                float p2 = __expf(s[i][a][2] - m0), p3 = __expf(s[i][a][3] - m0);
                pk[a].x = cvtpk(p0, p1);
                pk[a].y = cvtpk(p2, p3);
                sm += (p0 + p1) + (p2 + p3);   // f32 sum (pre-rounding)
            }
            // a=3: key 48 only; exp underflows to exactly 0 for pad lanes
            float p30 = __expf(s[i][3][0] - m0);
            pk[3].x = cvtpk(p30, 0.f);
            pk[3].y = 0u;
            sm += p30;
            sm += __shfl_xor(sm, 16);
            sm += __shfl_xor(sm, 32);
            inv[i] = 1.f / sm;
            u16* pb = i ? pb1 : pb0;
            #pragma unroll
            for (int a = 0; a < 4; ++a)
                *(uint2*)adr128(pb, lq, 32 * a + 8 * qd) = pk[a];
        }
        // single drain for both P buffers; pin schedule (r4-proven pattern)
        asm volatile("s_waitcnt lgkmcnt(0)" ::: "memory");
        __builtin_amdgcn_sched_barrier(0);
        f32x4 o[2][2] = {};
        __builtin_amdgcn_s_setprio(1);
        #pragma unroll
        for (int kt = 0; kt < 2; ++kt) {
            bf16x8 pf0 = *(const bf16x8*)adr128(pb0, lq, 64 * kt + 16 * qd);
            bf16x8 pf1 = *(const bf16x8*)adr128(pb1, lq, 64 * kt + 16 * qd);
            #pragma unroll
            for (int dt = 0; dt < 2; ++dt) {
                o[0][dt] = mfma16(vf[dt][kt], pf0, o[0][dt]);
                o[1][dt] = mfma16(vf[dt][kt], pf1, o[1][dt]);
            }
        }
        __builtin_amdgcn_s_setprio(0);
        #pragma unroll
        for (int i = 0; i < 2; ++i)
            #pragma unroll
            for (int dt = 0; dt < 2; ++dt) {
                uint2 px = pack4(o[i][dt][0] * inv[i], o[i][dt][1] * inv[i],
                                 o[i][dt][2] * inv[i], o[i][dt][3] * inv[i]);
                *(uint2*)adr256(SQ, (2 * half + i) * 16 + lq, 64 * h + 32 * dt + 8 * qd) = px;
            }
    }

    // ============ PHASE 3: out = x @ pjw + proj_b (coalesced float4 stores) ============
    {
        bf16x8 bw[2][4];
        #pragma unroll
        for (int n2 = 0; n2 < 2; ++n2)
            #pragma unroll
            for (int kt = 0; kt < 4; ++kt)
                bw[n2][kt] = *(const bf16x8*)(pjwp + (((nw + 4 * n2) * 4 + kt) * 64 + lane) * 8);
        __syncthreads();  // bar2: x complete in SQ
        f32x4 acc[2][2] = {};
        #pragma unroll
        for (int m2 = 0; m2 < 2; ++m2) {
            bf16x8 a[4];
            #pragma unroll
            for (int kt = 0; kt < 4; ++kt)
                a[kt] = *(const bf16x8*)adr256(SQ, (2 * mw + m2) * 16 + lq, kt * 64 + qd * 16);
            __builtin_amdgcn_s_setprio(1);
            #pragma unroll
            for (int n2 = 0; n2 < 2; ++n2)
                #pragma unroll
                for (int kt = 0; kt < 4; ++kt)
                    acc[m2][n2] = mfma16(bw[n2][kt], a[kt], acc[m2][n2]);
            __builtin_amdgcn_s_setprio(0);
        }
        float* outb = out + (size_t)b * NN * CC;
        #pragma unroll
        for (int n2 = 0; n2 < 2; ++n2) {
            const int cb0 = 16 * (nw + 4 * n2) + 4 * qd;
            const float4 bia = *(const float4*)(proj_b + cb0);
            #pragma unroll
            for (int m2 = 0; m2 < 2; ++m2) {
                const int tok = (2 * mw + m2) * 16 + lq;
                if (tok < NN) {
                    float4 vst;
                    vst.x = acc[m2][n2][0] + bia.x;
                    vst.y = acc[m2][n2][1] + bia.y;
                    vst.z = acc[m2][n2][2] + bia.z;
                    vst.w = acc[m2][n2][3] + bia.w;
                    *(float4*)(outb + tok * CC + cb0) = vst;
                }
            }
        }
    }
}

extern "C" void kernel_launch(void* const* d_in, const int* in_sizes, int n_in,
                              void* d_out, int out_size, void* d_ws, size_t ws_size,
                              hipStream_t stream) {
    const float* query      = (const float*)d_in[0];
    const float* source     = (const float*)d_in[1];
    const float* mask       = (const float*)d_in[2];
    const float* q_w        = (const float*)d_in[3];
    const float* q_b        = (const float*)d_in[4];
    const float* kv_w       = (const float*)d_in[5];
    const float* kv_b       = (const float*)d_in[6];
    const float* proj_w     = (const float*)d_in[7];
    const float* proj_b     = (const float*)d_in[8];
    const float* bias_table = (const float*)d_in[9];
    const int*   rel_idx    = (const int*)d_in[10];
    float* out = (float*)d_out;

    u16* cbt   = (u16*)d_ws;              // 1 Mi u16 = 2 MB
    u16* qwp   = cbt + 1048576;           // 16384 u16
    u16* kvwp  = qwp + 16384;             // 32768 u16
    u16* pjwp  = kvwp + 32768;            // 16384 u16
    float* qbs = (float*)(pjwp + 16384);  // 128 f32

    prep_cbt<<<4096, 256, 0, stream>>>(bias_table, rel_idx, mask, cbt);
    prep_w<<<257, 256, 0, stream>>>(q_w, q_b, kv_w, proj_w, qwp, kvwp, pjwp, qbs);
    wmha_main<<<BB, 512, 0, stream>>>(query, source, qwp, kvwp, pjwp, qbs,
                                      kv_b, proj_b, cbt, out);
}